// Round 1
// 6797.936 us; speedup vs baseline: 1.5969x; 1.5969x over previous
//
#include <hip/hip_runtime.h>
#include <math.h>

// ESN recurrence, persistent kernel, round 4 (W-in-registers).
// r3 diagnosis: LDS-read-instruction bound. 138 ds_read_b128/thread/step
// (W + h from LDS) x 16 waves = 2208 insts/CU/step x ~12cyc = 26.5k cyc
// = 11.0us/step == measured 10.86us. FMA was only ~8% of cycles.
// r4: W_hh|W_ih slice is step-invariant and only 144 floats/thread at 512
// threads -> hold it in VGPRs. Register micro-tile 4H x 4B per thread,
// K padded 1104->1152, split 32 ways (c=36). LDS k-loop reads drop
// 2208 -> 288 insts/CU/step (h only, th_i 4-way in-wave broadcast).
// New reduction: part[256][36] in LDS, XOR'd column (kidx^5*th_i) keeps
// writes <=2-way; 256 readers sum 8 f4 each (order-free), tanh, stores
// coalesced (h fast in lane order). Proven r3 group barrier kept.

#define T_STEPS 1000
#define NB      64
#define NI      80
#define NH      1024
#define KCAT    (NH + NI)        // 1104 = concat [h | x_t]
#define CH      36               // floats per K-chunk (K padded to 1152)
#define CH4     (CH / 4)         // 9 float4 per chunk
#define LSTR    1156             // hx row stride (floats): 1152 + 4 pad
#define PS      36               // part row stride (floats): 32 + 4 pad
#define NGROUPS 4
#define BTILE   16
#define HTILE   16
#define NTHR    512
#define LDS_FLOATS (BTILE * LSTR + 256 * PS)
#define LDS_BYTES  (LDS_FLOATS * 4)      // 110,848 B

__global__ __launch_bounds__(NTHR, 2) void esn_persistent(
    const float* __restrict__ x,        // [T,B,I]
    const int*   __restrict__ lengths,  // [B] descending
    const float* __restrict__ W_ih,     // [H,I]
    const float* __restrict__ W_hh,     // [H,H]
    float* __restrict__ out,            // [T,B,H]
    float*       h_buf,                 // ws: [2][B][H], zero-inited
    unsigned*    flags)                 // ws: [NGROUPS*64], zero-inited
{
    extern __shared__ float lds[];
    float* hx   = lds;                  // [BTILE][LSTR] : h_t row ++ x_t row ++ 0-pad
    float* part = lds + BTILE * LSTR;   // [256][PS] K-split partials

    const int tid   = threadIdx.x;
    const int bid   = blockIdx.x;
    const int g     = bid >> 6;         // 0..3 batch group
    const int htile = bid & 63;         // 0..63 H tile
    const int hi0   = htile * HTILE;
    const int gb0   = g * BTILE;

    const int kidx = tid >> 4;          // 0..31  K-chunk owner
    const int tile = tid & 15;
    const int th_i = tile >> 2;         // 0..3   H sub-tile (4 rows)
    const int th_j = tile & 3;          // 0..3   B sub-tile (4 batches)

    const int max_len = lengths[gb0];   // block-uniform (descending sort)
    const int len_b   = lengths[gb0 + ((tid >> 4) & 15)]; // valid for readers

    unsigned* gflags = flags + g * 64;

    // ---- W fragment -> registers: rows hi0+4*th_i..+3, cols kidx*36..+35 ----
    float4 wreg[4][CH4];                // 144 VGPRs, live whole kernel
    {
        const int k0 = kidx * CH;
        #pragma unroll
        for (int i = 0; i < 4; ++i) {
            const int hr = hi0 + th_i * 4 + i;
            const float* wh = W_hh + (size_t)hr * NH;
            const float* wi = W_ih + (size_t)hr * NI;
            #pragma unroll
            for (int kk = 0; kk < CH4; ++kk) {
                float v[4];
                #pragma unroll
                for (int c = 0; c < 4; ++c) {
                    const int gk = k0 + kk * 4 + c;
                    float w = 0.f;                  // pad cols [1104,1152) = 0
                    if (gk < NH)        w = wh[gk];
                    else if (gk < KCAT) w = wi[gk - NH];
                    v[c] = w;
                }
                wreg[i][kk] = float4{v[0], v[1], v[2], v[3]};
            }
        }
    }

    // ---- zero LDS once (hx pad cols must read as 0 in every step) ----
    for (int i = tid; i < LDS_FLOATS; i += NTHR) lds[i] = 0.f;
    __syncthreads();

    const int pc = kidx ^ (th_i * 5);   // XOR'd partial column: bank spread,
                                        // bijective per output row

    for (int t = 0; t < max_len; ++t) {
        const float* h_cur = h_buf + (size_t)(t & 1) * (NB * NH);
        float*       h_nxt = h_buf + (size_t)((t + 1) & 1) * (NB * NH);

        // ---- stage h: issue all 16 coherent 8B loads, then LDS writes ----
        {
            const unsigned long long* h8 =
                (const unsigned long long*)(h_cur + (size_t)gb0 * NH);
            unsigned long long vb[16];
            #pragma unroll
            for (int it = 0; it < 16; ++it)     // row it, ull-col tid
                vb[it] = __hip_atomic_load(h8 + (size_t)it * (NH / 2) + tid,
                           __ATOMIC_RELAXED, __HIP_MEMORY_SCOPE_AGENT);
            #pragma unroll
            for (int it = 0; it < 16; ++it)
                *(unsigned long long*)(&hx[it * LSTR + tid * 2]) = vb[it];
        }
        // ---- stage x_t: 16 rows x 20 float4 ----
        if (tid < BTILE * (NI / 4)) {
            const int r  = tid / (NI / 4);
            const int c4 = tid % (NI / 4);
            float4 v = ((const float4*)(x + ((size_t)t * NB + gb0 + r) * NI))[c4];
            *(float4*)(&hx[r * LSTR + NH + c4 * 4]) = v;
        }
        __syncthreads();

        // ---- 4H x 4B register micro-tile over this thread's 36-col K-chunk ----
        float acc[4][4];
        #pragma unroll
        for (int i = 0; i < 4; ++i)
            #pragma unroll
            for (int j = 0; j < 4; ++j) acc[i][j] = 0.f;

        #pragma unroll
        for (int j = 0; j < 4; ++j) {
            const float4* hj =
                (const float4*)(hx + (size_t)(th_j * 4 + j) * LSTR + kidx * CH);
            #pragma unroll
            for (int kk = 0; kk < CH4; ++kk) {
                const float4 hv = hj[kk];           // 4-way th_i broadcast
                #pragma unroll
                for (int i = 0; i < 4; ++i) {
                    acc[i][j] = fmaf(wreg[i][kk].x, hv.x,
                                fmaf(wreg[i][kk].y, hv.y,
                                fmaf(wreg[i][kk].z, hv.z,
                                fmaf(wreg[i][kk].w, hv.w, acc[i][j]))));
                }
            }
        }

        // ---- publish partials: part[h*16+b][pc], <=2-way banks by design ----
        #pragma unroll
        for (int i = 0; i < 4; ++i)
            #pragma unroll
            for (int j = 0; j < 4; ++j)
                part[(size_t)(((th_i * 4 + i) << 4) + th_j * 4 + j) * PS + pc]
                    = acc[i][j];
        __syncthreads();

        // ---- combine 32 partials, activate, publish (b = tid>>4, h = tid&15:
        //      h fast in lane order -> coalesced 64B stores) ----
        if (tid < 256) {
            const int b = tid >> 4;
            const int h = tid & 15;
            const float4* pr = (const float4*)(part + (size_t)((h << 4) + b) * PS);
            float4 e = pr[0], o = pr[1];
            #pragma unroll
            for (int n = 2; n < 8; n += 2) {
                const float4 a = pr[n], bq = pr[n + 1];
                e.x += a.x;  e.y += a.y;  e.z += a.z;  e.w += a.w;
                o.x += bq.x; o.y += bq.y; o.z += bq.z; o.w += bq.w;
            }
            const float accv = ((e.x + o.x) + (e.y + o.y))
                             + ((e.z + o.z) + (e.w + o.w));
            const int brow = gb0 + b;
            const int hrow = hi0 + h;
            const float hp = hx[b * LSTR + hrow];   // previous h for this (b,i)
            float hn, y;
            if (t < len_b) { hn = 0.5f * hp + 0.5f * tanhf(accv); y = hn; }
            else           { hn = hp; y = 0.f; }    // frozen / packed zero
            __hip_atomic_store(&h_nxt[(size_t)brow * NH + hrow], hn,
                               __ATOMIC_RELAXED, __HIP_MEMORY_SCOPE_AGENT);
            out[((size_t)t * NB + brow) * NH + hrow] = y;
        }

        // ---- per-group barrier (proven r3 structure) ----
        __builtin_amdgcn_s_waitcnt(0);   // stores of this wave complete at LLC
        __syncthreads();                 // => all waves' stores complete
        if (tid == 0)
            __hip_atomic_store(&gflags[htile], (unsigned)(t + 1),
                               __ATOMIC_RELAXED, __HIP_MEMORY_SCOPE_AGENT);
        if (tid < 64) {
            while (__hip_atomic_load(&gflags[tid],
                     __ATOMIC_RELAXED, __HIP_MEMORY_SCOPE_AGENT)
                   < (unsigned)(t + 1))
                __builtin_amdgcn_s_sleep(1);
        }
        __syncthreads();
    }

    // ---- tail: whole group past its max length -> zero outputs (float4) ----
    const float4 z4 = {0.f, 0.f, 0.f, 0.f};
    for (int p = tid; p < (T_STEPS - max_len) * 64; p += NTHR) {
        const int t = max_len + (p >> 6);
        const int o = p & 63;            // 16 b x 4 float4
        const int b = o >> 2;
        const int c = o & 3;
        *(float4*)(out + ((size_t)t * NB + gb0 + b) * NH + hi0 + c * 4) = z4;
    }
}

extern "C" void kernel_launch(void* const* d_in, const int* in_sizes, int n_in,
                              void* d_out, int out_size, void* d_ws, size_t ws_size,
                              hipStream_t stream) {
    const float* x       = (const float*)d_in[0];
    const int*   lengths = (const int*)  d_in[1];
    const float* W_ih    = (const float*)d_in[2];
    const float* W_hh    = (const float*)d_in[3];
    float*       out     = (float*)d_out;

    float*    h_buf = (float*)d_ws;                                   // 512 KB
    unsigned* flags = (unsigned*)((char*)d_ws + 2 * NB * NH * sizeof(float));

    hipMemsetAsync(d_ws, 0,
                   2 * NB * NH * sizeof(float) + NGROUPS * 64 * sizeof(unsigned),
                   stream);

    hipFuncSetAttribute((const void*)esn_persistent,
                        hipFuncAttributeMaxDynamicSharedMemorySize, LDS_BYTES);

    esn_persistent<<<dim3(NGROUPS * 64), dim3(NTHR), LDS_BYTES, stream>>>(
        x, lengths, W_ih, W_hh, out, h_buf, flags);
}